// Round 10
// baseline (149.907 us; speedup 1.0000x reference)
//
#include <hip/hip_runtime.h>
#include <hip/hip_bf16.h>

#define BB 16
#define CC 64
#define NN 4096      // H*W
#define MM 1024      // pooled spatial
#define LOG2E 1.4426950408889634f

typedef unsigned short u16;
typedef unsigned int u32;
typedef __attribute__((ext_vector_type(8))) short bf16x8;
typedef __attribute__((ext_vector_type(4))) float f32x4;

__device__ inline u16 f2bf(float f) {
    union { float f; u32 u; } v; v.f = f;
    return (u16)((v.u + 0x7FFFu + ((v.u >> 16) & 1u)) >> 16);
}
__device__ inline bf16x8 ld_bf16x8(const u16* p) {
    union { uint4 u; bf16x8 b; } c; c.u = *(const uint4*)p; return c.b;
}
__device__ inline bf16x8 ld2_bf16x8(const u16* p0, const u16* p1) {
    union { uint2 u[2]; bf16x8 b; } c;
    c.u[0] = *(const uint2*)p0;
    c.u[1] = *(const uint2*)p1;
    return c.b;
}
__device__ inline u32 cvt_pk_bf16(float lo, float hi) {
    __hip_bfloat162 h = __float22bfloat162_rn(make_float2(lo, hi));
    return *(u32*)&h;
}

// workspace (u16): theta_b [B][N][8] (pre-scaled by log2e) : 524288
//                  phi_b [B][M][8] : 131072 | gT_b [B][32][M] : 524288

// ---------------------------------------------------------------------------
// Kernel 1: MFMA 1x1 convs + 2x2 maxpool. grid (32,16): block = 128 px
// (2 image rows = 1 pooled row), no LDS. ALL 32 x-loads per lane hoisted
// ahead of any cvt/MFMA -> 32 independent vmem ops in flight per lane.
// ---------------------------------------------------------------------------
__global__ __launch_bounds__(256) void prep_kernel(
    const float* __restrict__ x, const float* __restrict__ w_theta,
    const float* __restrict__ w_phi, const float* __restrict__ w_g,
    u16* __restrict__ theta_b, u16* __restrict__ phi_b, u16* __restrict__ gT_b)
{
    const int t = threadIdx.x, w = t >> 6, lane = t & 63;
    const int m16 = lane & 15, quad = lane >> 4;
    const int b = blockIdx.y, bx = blockIdx.x;
    const int nbase = bx * 128;

    const float* xb = x + (size_t)b * CC * NN;

    // ---- issue ALL x loads first (independent; fills the vmem queue) ----
    float xr[32];
    #pragma unroll
    for (int r = 0; r < 2; ++r)
        #pragma unroll
        for (int kc = 0; kc < 2; ++kc)
            #pragma unroll
            for (int jj = 0; jj < 8; ++jj)
                xr[r * 16 + kc * 8 + jj] =
                    xb[(size_t)(kc * 32 + quad * 8 + jj) * NN + nbase + r * 64 + w * 16 + m16];

    // ---- weight A-frags: f0 = theta(m16<8)/phi(m16>=8), f1/f2 = g ----
    bf16x8 A[3][2];
    {
        const float* row0 = (m16 < 8) ? (w_theta + m16 * 64) : (w_phi + (m16 - 8) * 64);
        const float* rows[3] = { row0, w_g + m16 * 64, w_g + (16 + m16) * 64 };
        #pragma unroll
        for (int f = 0; f < 3; ++f)
            #pragma unroll
            for (int kc = 0; kc < 2; ++kc) {
                const float* p = rows[f] + kc * 32 + quad * 8;
                const float4 f0 = *(const float4*)p;
                const float4 f1 = *(const float4*)(p + 4);
                union { u32 d[4]; bf16x8 v; } a;
                a.d[0] = cvt_pk_bf16(f0.x, f0.y);
                a.d[1] = cvt_pk_bf16(f0.z, f0.w);
                a.d[2] = cvt_pk_bf16(f1.x, f1.y);
                a.d[3] = cvt_pk_bf16(f1.z, f1.w);
                A[f][kc] = a.v;
            }
    }

    const f32x4 zero4 = {0.f, 0.f, 0.f, 0.f};
    f32x4 acc[2][3];
    #pragma unroll
    for (int r = 0; r < 2; ++r)
        #pragma unroll
        for (int f = 0; f < 3; ++f) acc[r][f] = zero4;

    #pragma unroll
    for (int r = 0; r < 2; ++r)
        #pragma unroll
        for (int kc = 0; kc < 2; ++kc) {
            const float* xv = &xr[r * 16 + kc * 8];
            union { u32 d[4]; bf16x8 v; } bxf;
            bxf.d[0] = cvt_pk_bf16(xv[0], xv[1]);
            bxf.d[1] = cvt_pk_bf16(xv[2], xv[3]);
            bxf.d[2] = cvt_pk_bf16(xv[4], xv[5]);
            bxf.d[3] = cvt_pk_bf16(xv[6], xv[7]);
            #pragma unroll
            for (int f = 0; f < 3; ++f)
                acc[r][f] = __builtin_amdgcn_mfma_f32_16x16x32_bf16(A[f][kc], bxf.v, acc[r][f], 0, 0, 0);
        }

    if (quad < 2) {
        #pragma unroll
        for (int r = 0; r < 2; ++r) {
            const int px = nbase + r * 64 + w * 16 + m16;
            uint2 v;
            v.x = cvt_pk_bf16(acc[r][0][0] * LOG2E, acc[r][0][1] * LOG2E);
            v.y = cvt_pk_bf16(acc[r][0][2] * LOG2E, acc[r][0][3] * LOG2E);
            *(uint2*)(theta_b + ((size_t)b * NN + px) * 8 + quad * 4) = v;
        }
    }

    float pv[3][4];
    #pragma unroll
    for (int f = 0; f < 3; ++f)
        #pragma unroll
        for (int rr = 0; rr < 4; ++rr) {
            float h0 = acc[0][f][rr]; h0 = fmaxf(h0, __shfl_xor(h0, 1, 64));
            float h1 = acc[1][f][rr]; h1 = fmaxf(h1, __shfl_xor(h1, 1, 64));
            pv[f][rr] = fmaxf(h0, h1);
        }

    if ((m16 & 1) == 0) {
        const int pcol = w * 8 + (m16 >> 1);
        const int m = bx * 32 + pcol;
        if (quad >= 2) {
            uint2 v;
            v.x = cvt_pk_bf16(pv[0][0], pv[0][1]);
            v.y = cvt_pk_bf16(pv[0][2], pv[0][3]);
            *(uint2*)(phi_b + ((size_t)b * MM + m) * 8 + (quad - 2) * 4) = v;
        }
        #pragma unroll
        for (int f = 1; f < 3; ++f)
            #pragma unroll
            for (int rr = 0; rr < 4; ++rr) {
                const int d = (f - 1) * 16 + quad * 4 + rr;
                gT_b[(size_t)b * 32 * MM + (size_t)d * MM + m] = f2bf(pv[f][rr]);
            }
    }
}

// ---------------------------------------------------------------------------
// Kernel 2: barrier-free fused attention + output conv + residual, with
// DEPTH-2 REGISTER PREFETCH: fully-unrolled K-loop; iteration k consumes
// frags loaded at k-2 and issues loads for k+2 -> loads have >=2 iterations
// of compute before their first use, so they stay in flight (vmcnt>0) and
// the ~200-400cyc L2 latency is hidden. No barriers -> nothing drains the
// vmem queue. grid (64,16) = 4 blocks/CU (5 KB LDS), 16 waves/CU.
// phi rows loaded by ALL lanes (garbage k-slots * theta's exact zeros = 0).
// ---------------------------------------------------------------------------
__global__ __launch_bounds__(256, 4) void attn_out_kernel(
    const u16* __restrict__ theta_b, const u16* __restrict__ phi_b,
    const u16* __restrict__ gT_b, const float* __restrict__ w_o,
    const float* __restrict__ x, const float* __restrict__ gamma_p,
    float* __restrict__ out)
{
    __shared__ u16 oS[64 * 40];      // [q_local][d + pad8], 5 KB

    const int t = threadIdx.x, w = t >> 6, lane = t & 63;
    const int m16 = lane & 15, quad = lane >> 4;
    const int b = blockIdx.y, qbase = blockIdx.x * 64;

    const u16* phg = phi_b + (size_t)b * MM * 8;
    const u16* gtg = gT_b + (size_t)b * 32 * MM;

    // per-lane base pointers (loop adds only kb offsets)
    const u16* ph0b = phg + (size_t)m16 * 8;
    const u16* ph1b = phg + (size_t)(16 + m16) * 8;
    const u16* g0b  = gtg + (size_t)m16 * MM + quad * 4;
    const u16* g1b  = gtg + (size_t)(16 + m16) * MM + quad * 4;

    // persistent theta B-frag (quad0 real, rest exact zero)
    bf16x8 thB = {0, 0, 0, 0, 0, 0, 0, 0};
    if (quad == 0)
        thB = ld_bf16x8(theta_b + ((size_t)b * NN + qbase + w * 16 + m16) * 8);

    bf16x8 woA[4];
    #pragma unroll
    for (int cf = 0; cf < 4; ++cf) {
        const float* wp = w_o + (cf * 16 + m16) * 32 + quad * 8;
        const float4 f0 = *(const float4*)wp;
        const float4 f1 = *(const float4*)(wp + 4);
        union { u32 d[4]; bf16x8 v; } a;
        a.d[0] = cvt_pk_bf16(f0.x, f0.y);
        a.d[1] = cvt_pk_bf16(f0.z, f0.w);
        a.d[2] = cvt_pk_bf16(f1.x, f1.y);
        a.d[3] = cvt_pk_bf16(f1.z, f1.w);
        woA[cf] = a.v;
    }
    bf16x8 onesA;
    #pragma unroll
    for (int i = 0; i < 8; ++i) onesA[i] = (short)0x3F80;

    const f32x4 zero4 = {0.f, 0.f, 0.f, 0.f};
    f32x4 oT0 = zero4, oT1 = zero4, lacc = zero4;

    // ---- depth-2 prefetch pipeline (fully unrolled -> all regs SSA) ----
    bf16x8 nA0[2], nA1[2], nG0[2], nG1[2];
    #pragma unroll
    for (int s = 0; s < 2; ++s) {
        const int kb = s * 32;
        nA0[s] = ld_bf16x8(ph0b + (size_t)kb * 8);
        nA1[s] = ld_bf16x8(ph1b + (size_t)kb * 8);
        nG0[s] = ld2_bf16x8(g0b + kb, g0b + kb + 16);
        nG1[s] = ld2_bf16x8(g1b + kb, g1b + kb + 16);
    }

    #pragma unroll
    for (int kblk = 0; kblk < 32; ++kblk) {
        const int s = kblk & 1;
        const bf16x8 cA0 = nA0[s], cA1 = nA1[s], cG0 = nG0[s], cG1 = nG1[s];

        if (kblk < 30) {                      // issue loads for kblk+2
            const int kb = (kblk + 2) * 32;
            nA0[s] = ld_bf16x8(ph0b + (size_t)kb * 8);
            nA1[s] = ld_bf16x8(ph1b + (size_t)kb * 8);
            nG0[s] = ld2_bf16x8(g0b + kb, g0b + kb + 16);
            nG1[s] = ld2_bf16x8(g1b + kb, g1b + kb + 16);
        }

        // S^T = mfma(phi, theta): D[m=key][n=q]
        const f32x4 Sa = __builtin_amdgcn_mfma_f32_16x16x32_bf16(cA0, thB, zero4, 0, 0, 0);
        const f32x4 Sb = __builtin_amdgcn_mfma_f32_16x16x32_bf16(cA1, thB, zero4, 0, 0, 0);

        union { u32 d[4]; bf16x8 v; } pb;
        pb.d[0] = cvt_pk_bf16(exp2f(Sa[0]), exp2f(Sa[1]));
        pb.d[1] = cvt_pk_bf16(exp2f(Sa[2]), exp2f(Sa[3]));
        pb.d[2] = cvt_pk_bf16(exp2f(Sb[0]), exp2f(Sb[1]));
        pb.d[3] = cvt_pk_bf16(exp2f(Sb[2]), exp2f(Sb[3]));

        oT0  = __builtin_amdgcn_mfma_f32_16x16x32_bf16(cG0, pb.v, oT0, 0, 0, 0);
        oT1  = __builtin_amdgcn_mfma_f32_16x16x32_bf16(cG1, pb.v, oT1, 0, 0, 0);
        lacc = __builtin_amdgcn_mfma_f32_16x16x32_bf16(onesA, pb.v, lacc, 0, 0, 0);
    }

    // normalize in-lane; transpose via oS (wave-private rows -> no barrier)
    const float inv = 1.0f / lacc[0];
    u16* orow = oS + (size_t)(w * 16 + m16) * 40;
    {
        uint2 a, b2;
        a.x  = cvt_pk_bf16(oT0[0] * inv, oT0[1] * inv);
        a.y  = cvt_pk_bf16(oT0[2] * inv, oT0[3] * inv);
        b2.x = cvt_pk_bf16(oT1[0] * inv, oT1[1] * inv);
        b2.y = cvt_pk_bf16(oT1[2] * inv, oT1[3] * inv);
        *(uint2*)(orow + quad * 4) = a;
        *(uint2*)(orow + 16 + quad * 4) = b2;
    }

    // output conv: D[m=c][n=px] = w_o @ o; out = gamma*D + x
    const bf16x8 oB = ld_bf16x8(oS + (size_t)(w * 16 + m16) * 40 + quad * 8);
    const float gamma = *gamma_p;
    #pragma unroll
    for (int cf = 0; cf < 4; ++cf) {
        const f32x4 D = __builtin_amdgcn_mfma_f32_16x16x32_bf16(woA[cf], oB, zero4, 0, 0, 0);
        #pragma unroll
        for (int rr = 0; rr < 4; ++rr) {
            const int cch = cf * 16 + quad * 4 + rr;
            const size_t adr = ((size_t)b * CC + cch) * NN + qbase + w * 16 + m16;
            out[adr] = gamma * D[rr] + x[adr];
        }
    }
}

// ---------------------------------------------------------------------------
extern "C" void kernel_launch(void* const* d_in, const int* in_sizes, int n_in,
                              void* d_out, int out_size, void* d_ws, size_t ws_size,
                              hipStream_t stream) {
    const float* x       = (const float*)d_in[0];
    const float* w_theta = (const float*)d_in[1];
    const float* w_phi   = (const float*)d_in[2];
    const float* w_g     = (const float*)d_in[3];
    const float* w_o     = (const float*)d_in[4];
    const float* gamma   = (const float*)d_in[5];

    u16* theta_b = (u16*)d_ws;                      // 524288
    u16* phi_b   = theta_b + 524288;                // 131072
    u16* gT_b    = phi_b + 131072;                  // 524288
    float* out   = (float*)d_out;

    prep_kernel<<<dim3(32, 16), 256, 0, stream>>>(x, w_theta, w_phi, w_g,
                                                  theta_b, phi_b, gT_b);
    attn_out_kernel<<<dim3(64, 16), 256, 0, stream>>>(theta_b, phi_b, gT_b,
                                                      w_o, x, gamma, out);
}

// Round 11
// 110.241 us; speedup vs baseline: 1.3598x; 1.3598x over previous
//
#include <hip/hip_runtime.h>
#include <hip/hip_bf16.h>

#define BB 16
#define CC 64
#define NN 4096      // H*W
#define MM 1024      // pooled spatial
#define LOG2E 1.4426950408889634f

typedef unsigned short u16;
typedef unsigned int u32;
typedef __attribute__((ext_vector_type(8))) short bf16x8;
typedef __attribute__((ext_vector_type(4))) float f32x4;

__device__ inline u16 f2bf(float f) {
    union { float f; u32 u; } v; v.f = f;
    return (u16)((v.u + 0x7FFFu + ((v.u >> 16) & 1u)) >> 16);
}
__device__ inline bf16x8 ld_bf16x8(const u16* p) {
    union { uint4 u; bf16x8 b; } c; c.u = *(const uint4*)p; return c.b;
}
__device__ inline bf16x8 ld2_bf16x8(const u16* p0, const u16* p1) {
    union { uint2 u[2]; bf16x8 b; } c;
    c.u[0] = *(const uint2*)p0;
    c.u[1] = *(const uint2*)p1;
    return c.b;
}
__device__ inline u32 cvt_pk_bf16(float lo, float hi) {
    __hip_bfloat162 h = __float22bfloat162_rn(make_float2(lo, hi));
    return *(u32*)&h;
}

// workspace (u16): theta_b [B][N][8] (pre-scaled by log2e) : 524288
//                  phi_b [B][M][8] : 131072 | gT_b [B][32][M] : 524288

// ---------------------------------------------------------------------------
// Kernel 1: MFMA 1x1 convs + 2x2 maxpool, retiled for 2x occupancy.
// grid (64,16): bx -> row-pair rp = bx>>1, col-half c0 = (bx&1)*32.
// Wave w owns 8 cols x 2 rows as ONE B-frag (n-slot = r*8+cc) -> vertical
// pool = shfl_xor(8), horizontal = shfl_xor(1), both in-wave. 16 loads and
// 6 MFMAs per wave (half of R10) at 16 waves/CU (double of R10).
// ---------------------------------------------------------------------------
__global__ __launch_bounds__(256, 4) void prep_kernel(
    const float* __restrict__ x, const float* __restrict__ w_theta,
    const float* __restrict__ w_phi, const float* __restrict__ w_g,
    u16* __restrict__ theta_b, u16* __restrict__ phi_b, u16* __restrict__ gT_b)
{
    const int t = threadIdx.x, w = t >> 6, lane = t & 63;
    const int m16 = lane & 15, quad = lane >> 4;
    const int b = blockIdx.y, bx = blockIdx.x;
    const int rp = bx >> 1, ch = bx & 1;
    // this lane's pixel (n-slot m16 = r*8+cc)
    const int px = (2 * rp + (m16 >> 3)) * 64 + ch * 32 + w * 8 + (m16 & 7);

    const float* xb = x + (size_t)b * CC * NN;

    // ---- all 16 x-loads first (independent, fills vmem queue) ----
    float xr[16];
    #pragma unroll
    for (int kc = 0; kc < 2; ++kc)
        #pragma unroll
        for (int jj = 0; jj < 8; ++jj)
            xr[kc * 8 + jj] = xb[(size_t)(kc * 32 + quad * 8 + jj) * NN + px];

    // ---- weight A-frags: f0 = theta(m16<8)/phi(m16>=8), f1/f2 = g ----
    bf16x8 A[3][2];
    {
        const float* row0 = (m16 < 8) ? (w_theta + m16 * 64) : (w_phi + (m16 - 8) * 64);
        const float* rows[3] = { row0, w_g + m16 * 64, w_g + (16 + m16) * 64 };
        #pragma unroll
        for (int f = 0; f < 3; ++f)
            #pragma unroll
            for (int kc = 0; kc < 2; ++kc) {
                const float* p = rows[f] + kc * 32 + quad * 8;
                const float4 f0 = *(const float4*)p;
                const float4 f1 = *(const float4*)(p + 4);
                union { u32 d[4]; bf16x8 v; } a;
                a.d[0] = cvt_pk_bf16(f0.x, f0.y);
                a.d[1] = cvt_pk_bf16(f0.z, f0.w);
                a.d[2] = cvt_pk_bf16(f1.x, f1.y);
                a.d[3] = cvt_pk_bf16(f1.z, f1.w);
                A[f][kc] = a.v;
            }
    }

    const f32x4 zero4 = {0.f, 0.f, 0.f, 0.f};
    f32x4 acc[3] = {zero4, zero4, zero4};

    #pragma unroll
    for (int kc = 0; kc < 2; ++kc) {
        const float* xv = &xr[kc * 8];
        union { u32 d[4]; bf16x8 v; } bxf;
        bxf.d[0] = cvt_pk_bf16(xv[0], xv[1]);
        bxf.d[1] = cvt_pk_bf16(xv[2], xv[3]);
        bxf.d[2] = cvt_pk_bf16(xv[4], xv[5]);
        bxf.d[3] = cvt_pk_bf16(xv[6], xv[7]);
        #pragma unroll
        for (int f = 0; f < 3; ++f)
            acc[f] = __builtin_amdgcn_mfma_f32_16x16x32_bf16(A[f][kc], bxf.v, acc[f], 0, 0, 0);
    }

    // theta (frag0 quads 0,1 hold ch quad*4+rr for px = n-slot m16)
    if (quad < 2) {
        uint2 v;
        v.x = cvt_pk_bf16(acc[0][0] * LOG2E, acc[0][1] * LOG2E);
        v.y = cvt_pk_bf16(acc[0][2] * LOG2E, acc[0][3] * LOG2E);
        *(uint2*)(theta_b + ((size_t)b * NN + px) * 8 + quad * 4) = v;
    }

    // 2x2 pool fully in-wave: horizontal xor(1) (cc pair), vertical xor(8) (r pair)
    float pv[3][4];
    #pragma unroll
    for (int f = 0; f < 3; ++f)
        #pragma unroll
        for (int rr = 0; rr < 4; ++rr) {
            float h = acc[f][rr];
            h = fmaxf(h, __shfl_xor(h, 1, 64));
            h = fmaxf(h, __shfl_xor(h, 8, 64));
            pv[f][rr] = h;
        }

    if ((m16 & 9) == 0) {     // m16 in {0,2,4,6}
        const int m = rp * 32 + ch * 16 + w * 4 + (m16 >> 1);
        if (quad >= 2) {      // phi ch = (quad-2)*4 + rr
            uint2 v;
            v.x = cvt_pk_bf16(pv[0][0], pv[0][1]);
            v.y = cvt_pk_bf16(pv[0][2], pv[0][3]);
            *(uint2*)(phi_b + ((size_t)b * MM + m) * 8 + (quad - 2) * 4) = v;
        }
        #pragma unroll
        for (int f = 1; f < 3; ++f)
            #pragma unroll
            for (int rr = 0; rr < 4; ++rr) {
                const int d = (f - 1) * 16 + quad * 4 + rr;
                gT_b[(size_t)b * 32 * MM + (size_t)d * MM + m] = f2bf(pv[f][rr]);
            }
    }
}

// ---------------------------------------------------------------------------
// Kernel 2: LDS-staged fused attention + output conv + residual, tuned for
// 8 blocks/CU (32 waves/CU = 2x all previous rounds). LDS 15.5 KB/block;
// in-loop register state kept ~55 VGPR (w_o frags loaded AFTER the K-loop).
// 8 chunks of 128 keys; per kblk: S^T = mfma(phi,theta), exp2 -> P B-frag in
// registers (K-permuted), O^T += mfma(g,P), denom += mfma(ones,P).
// ---------------------------------------------------------------------------
__global__ __launch_bounds__(256, 8) void attn_out_kernel(
    const u16* __restrict__ theta_b, const u16* __restrict__ phi_b,
    const u16* __restrict__ gT_b, const float* __restrict__ w_o,
    const float* __restrict__ x, const float* __restrict__ gamma_p,
    float* __restrict__ out)
{
    __shared__ u16 phS[128 * 8];     // chunk phi [key][8], 2 KB
    __shared__ u16 gS[32 * 136];     // chunk gT [d][128+pad8], 8.5 KB
    __shared__ u16 oS[64 * 40];      // [q_local][d+pad8], 5 KB

    const int t = threadIdx.x, w = t >> 6, lane = t & 63;
    const int m16 = lane & 15, quad = lane >> 4;
    const int b = blockIdx.y, qbase = blockIdx.x * 64;

    const u16* phg = phi_b + (size_t)b * MM * 8;
    const u16* gtg = gT_b + (size_t)b * 32 * MM;

    // persistent theta B-frag (quad0 real, rest exact zero)
    bf16x8 thB = {0, 0, 0, 0, 0, 0, 0, 0};
    if (quad == 0)
        thB = ld_bf16x8(theta_b + ((size_t)b * NN + qbase + w * 16 + m16) * 8);

    bf16x8 onesA;
    #pragma unroll
    for (int i = 0; i < 8; ++i) onesA[i] = (short)0x3F80;

    const f32x4 zero4 = {0.f, 0.f, 0.f, 0.f};
    f32x4 oT0 = zero4, oT1 = zero4, lacc = zero4;

    for (int c = 0; c < 8; ++c) {
        __syncthreads();                       // protect prev chunk's readers
        // stage phi: 128 rows x 16 B, threads 0..127
        if (t < 128)
            *(uint4*)(phS + t * 8) = *(const uint4*)(phg + (size_t)(c * 128 + t) * 8);
        // stage g: 32 rows x 256 B -> 512 uint4 slots, 2 per thread
        #pragma unroll
        for (int i = 0; i < 2; ++i) {
            const int f = i * 256 + t, d = f >> 4, part = f & 15;
            *(uint4*)(gS + d * 136 + part * 8) =
                *(const uint4*)(gtg + (size_t)d * MM + c * 128 + part * 8);
        }
        __syncthreads();

        #pragma unroll
        for (int kblk = 0; kblk < 4; ++kblk) {
            const int kb = kblk * 32;
            const bf16x8 phA0 = ld_bf16x8(phS + (kb + m16) * 8);
            const bf16x8 phA1 = ld_bf16x8(phS + (kb + 16 + m16) * 8);
            const u16* g0p = gS + m16 * 136 + kb + quad * 4;
            const u16* g1p = gS + (16 + m16) * 136 + kb + quad * 4;
            const bf16x8 gA0 = ld2_bf16x8(g0p, g0p + 16);
            const bf16x8 gA1 = ld2_bf16x8(g1p, g1p + 16);

            const f32x4 Sa = __builtin_amdgcn_mfma_f32_16x16x32_bf16(phA0, thB, zero4, 0, 0, 0);
            const f32x4 Sb = __builtin_amdgcn_mfma_f32_16x16x32_bf16(phA1, thB, zero4, 0, 0, 0);

            union { u32 d[4]; bf16x8 v; } pb;
            pb.d[0] = cvt_pk_bf16(exp2f(Sa[0]), exp2f(Sa[1]));
            pb.d[1] = cvt_pk_bf16(exp2f(Sa[2]), exp2f(Sa[3]));
            pb.d[2] = cvt_pk_bf16(exp2f(Sb[0]), exp2f(Sb[1]));
            pb.d[3] = cvt_pk_bf16(exp2f(Sb[2]), exp2f(Sb[3]));

            oT0  = __builtin_amdgcn_mfma_f32_16x16x32_bf16(gA0, pb.v, oT0, 0, 0, 0);
            oT1  = __builtin_amdgcn_mfma_f32_16x16x32_bf16(gA1, pb.v, oT1, 0, 0, 0);
            lacc = __builtin_amdgcn_mfma_f32_16x16x32_bf16(onesA, pb.v, lacc, 0, 0, 0);
        }
    }

    // normalize in-lane; transpose via oS (wave-private rows -> no barrier)
    const float inv = 1.0f / lacc[0];
    u16* orow = oS + (size_t)(w * 16 + m16) * 40;
    {
        uint2 a, b2;
        a.x  = cvt_pk_bf16(oT0[0] * inv, oT0[1] * inv);
        a.y  = cvt_pk_bf16(oT0[2] * inv, oT0[3] * inv);
        b2.x = cvt_pk_bf16(oT1[0] * inv, oT1[1] * inv);
        b2.y = cvt_pk_bf16(oT1[2] * inv, oT1[3] * inv);
        *(uint2*)(orow + quad * 4) = a;
        *(uint2*)(orow + 16 + quad * 4) = b2;
    }

    // w_o A-frags loaded only now (register lifetime outside the K-loop)
    const bf16x8 oB = ld_bf16x8(oS + (size_t)(w * 16 + m16) * 40 + quad * 8);
    const float gamma = *gamma_p;
    #pragma unroll
    for (int cf = 0; cf < 4; ++cf) {
        const float* wp = w_o + (cf * 16 + m16) * 32 + quad * 8;
        const float4 f0 = *(const float4*)wp;
        const float4 f1 = *(const float4*)(wp + 4);
        union { u32 d[4]; bf16x8 v; } a;
        a.d[0] = cvt_pk_bf16(f0.x, f0.y);
        a.d[1] = cvt_pk_bf16(f0.z, f0.w);
        a.d[2] = cvt_pk_bf16(f1.x, f1.y);
        a.d[3] = cvt_pk_bf16(f1.z, f1.w);
        const f32x4 D = __builtin_amdgcn_mfma_f32_16x16x32_bf16(a.v, oB, zero4, 0, 0, 0);
        #pragma unroll
        for (int rr = 0; rr < 4; ++rr) {
            const int cch = cf * 16 + quad * 4 + rr;
            const size_t adr = ((size_t)b * CC + cch) * NN + qbase + w * 16 + m16;
            out[adr] = gamma * D[rr] + x[adr];
        }
    }
}

// ---------------------------------------------------------------------------
extern "C" void kernel_launch(void* const* d_in, const int* in_sizes, int n_in,
                              void* d_out, int out_size, void* d_ws, size_t ws_size,
                              hipStream_t stream) {
    const float* x       = (const float*)d_in[0];
    const float* w_theta = (const float*)d_in[1];
    const float* w_phi   = (const float*)d_in[2];
    const float* w_g     = (const float*)d_in[3];
    const float* w_o     = (const float*)d_in[4];
    const float* gamma   = (const float*)d_in[5];

    u16* theta_b = (u16*)d_ws;                      // 524288
    u16* phi_b   = theta_b + 524288;                // 131072
    u16* gT_b    = phi_b + 131072;                  // 524288
    float* out   = (float*)d_out;

    prep_kernel<<<dim3(64, 16), 256, 0, stream>>>(x, w_theta, w_phi, w_g,
                                                  theta_b, phi_b, gT_b);
    attn_out_kernel<<<dim3(64, 16), 256, 0, stream>>>(theta_b, phi_b, gT_b,
                                                      w_o, x, gamma, out);
}